// Round 9
// baseline (243.578 us; speedup 1.0000x reference)
//
#include <hip/hip_runtime.h>

typedef __bf16 bf16_t;
typedef bf16_t bf16x8 __attribute__((ext_vector_type(8)));
typedef bf16_t bf16x4 __attribute__((ext_vector_type(4)));
typedef float f32x4 __attribute__((ext_vector_type(4)));
typedef unsigned short u16;
typedef unsigned int u32;

#define E_TOT 524288
#define MT 64
#define NBLK (E_TOT / MT)   // 8192

__device__ __forceinline__ u16 f2bf(float f) {
  u32 u = __builtin_bit_cast(u32, f);
  u += 0x7FFFu + ((u >> 16) & 1u);
  return (u16)(u >> 16);
}

__device__ __forceinline__ bf16x8 pack8(f32x4 a, f32x4 b) {
  bf16x8 p;
  p[0] = (bf16_t)a[0]; p[1] = (bf16_t)a[1]; p[2] = (bf16_t)a[2]; p[3] = (bf16_t)a[3];
  p[4] = (bf16_t)b[0]; p[5] = (bf16_t)b[1]; p[6] = (bf16_t)b[2]; p[7] = (bf16_t)b[3];
  return p;
}

// W1F frag-ordered: idx = (((kb*4+wc)*4+nf)*64+l)*8+e   (kb = 32-wide k-chunk, 0..11)
//   holds W1^T[n=wc*64+nf*16+(l&15)][k=kb*32+(l>>4)*8+e] = W1[k*256+n]
__global__ void prep_w1f(const float* __restrict__ W1, u16* __restrict__ W1F) {
  int t = blockIdx.x * 256 + threadIdx.x;  // 0..98303
  if (t < 98304) {
    int e  = t & 7;
    int l  = (t >> 3) & 63;
    int nf = (t >> 9) & 3;
    int wc = (t >> 11) & 3;
    int kb = t >> 13;
    int n = wc * 64 + nf * 16 + (l & 15);
    int k = kb * 32 + ((l >> 4) << 3) + e;
    W1F[t] = f2bf(W1[k * 256 + n]);
  }
}

// W2F frag-ordered: idx = ((ks*4+n2f)*64+l)*8+e
//   holds W2^T[n2=n2f*16+(l&15)][k=ks*32+(l>>4)*8+e] = W2[k*64+n2]
__global__ void prep_w2f(const float* __restrict__ W2, u16* __restrict__ W2F) {
  int t = blockIdx.x * 256 + threadIdx.x;  // 0..16383
  if (t < 16384) {
    int e   = t & 7;
    int l   = (t >> 3) & 63;
    int n2f = (t >> 9) & 3;
    int ks  = t >> 11;
    int n2 = n2f * 16 + (l & 15);
    int k  = ks * 32 + ((l >> 4) << 3) + e;
    W2F[t] = f2bf(W2[k * 64 + n2]);
  }
}

// Fused: x = [src|dest|edge|u[batch]] (E x 384); h = relu(x@W1+b1); out = h@W2+b2
// Swapped layer-1: acc = mfma(W_frag, x_frag) -> h^T fragments.
__global__ void __launch_bounds__(256) edge_fused(
    const float* __restrict__ src, const float* __restrict__ dst,
    const float* __restrict__ ea, const float* __restrict__ u,
    const int* __restrict__ batch, const u16* __restrict__ W1F,
    const float* __restrict__ b1, const u16* __restrict__ W2F,
    const float* __restrict__ b2, float* __restrict__ out)
{
  // 32 KB LDS: As dbuf 2 x 4096 u16 (BK=64) during K-loop; Hs[64][256] overlays.
  __shared__ __align__(16) u16 smem[16384];
  u16* As = smem;
  u16* Hs = smem;

  const int t    = threadIdx.x;
  const int wid  = t >> 6;
  const int lane = t & 63;
  const int lr   = lane & 15;
  const int lg   = lane >> 4;
  const int e0   = blockIdx.x * MT;
  const int r    = t >> 2;        // A row owned by this thread (0..63)
  const int jc   = t & 3;         // 16-f32 col group within 64-k chunk
  const int bidx = batch[e0 + r];
  const int u0   = 2 * jc;        // thread's two 16B units within the row

  auto loadA = [&](int c, f32x4* ra) {
    const float* p;
    if (c < 2)       p = src + (size_t)(e0 + r) * 128 + c * 64 + jc * 16;
    else if (c < 4)  p = dst + (size_t)(e0 + r) * 128 + (c - 2) * 64 + jc * 16;
    else if (c == 4) p = ea + (size_t)(e0 + r) * 64 + jc * 16;
    else             p = u + (size_t)bidx * 64 + jc * 16;
    ra[0] = *(const f32x4*)p;
    ra[1] = *(const f32x4*)(p + 4);
    ra[2] = *(const f32x4*)(p + 8);
    ra[3] = *(const f32x4*)(p + 12);
  };
  // W frags for 64-k chunk c: two 32-k halves ks=0,1 -> old kb = 2c+ks
  auto loadW1 = [&](int c, bf16x8* wf) {
    #pragma unroll
    for (int ks = 0; ks < 2; ++ks) {
      const u16* p = W1F + ((size_t)((2 * c + ks) * 4 + wid) * 4) * 512 + lane * 8;
      wf[ks * 4 + 0] = *(const bf16x8*)(p);
      wf[ks * 4 + 1] = *(const bf16x8*)(p + 512);
      wf[ks * 4 + 2] = *(const bf16x8*)(p + 1024);
      wf[ks * 4 + 3] = *(const bf16x8*)(p + 1536);
    }
  };

  // prologue
  f32x4 ra[4];
  bf16x8 wf[8];
  loadA(0, ra);
  loadW1(0, wf);

  f32x4 acc[4][4];   // [nf][mf] h^T frags
  #pragma unroll
  for (int i = 0; i < 4; ++i)
    #pragma unroll
    for (int j = 0; j < 4; ++j)
      acc[i][j] = (f32x4){0.f, 0.f, 0.f, 0.f};

  // ---- K loop: 6 chunks of 64; one barrier per chunk; no vmcnt drain ----
  #pragma unroll
  for (int kb = 0; kb < 6; ++kb) {
    u16* Ab = As + (kb & 1) * 4096;

    // pack + write A(kb): 2 swizzled b128 ds_writes (waits only ra's own loads)
    {
      bf16x8 lo = pack8(ra[0], ra[1]);
      bf16x8 hi = pack8(ra[2], ra[3]);
      *(bf16x8*)&Ab[(r * 8 + (u0 ^ (r & 7))) * 8]       = lo;
      *(bf16x8*)&Ab[(r * 8 + ((u0 + 1) ^ (r & 7))) * 8] = hi;
    }
    if (kb < 5) loadA(kb + 1, ra);   // refill; window = 1 full chunk

    // publish LDS writes only; global prefetches stay in flight
    asm volatile("s_waitcnt lgkmcnt(0)" ::: "memory");
    __builtin_amdgcn_s_barrier();
    __builtin_amdgcn_sched_barrier(0);

    __builtin_amdgcn_s_setprio(1);
    #pragma unroll
    for (int ks = 0; ks < 2; ++ks) {
      bf16x8 af[4];
      #pragma unroll
      for (int mf = 0; mf < 4; ++mf) {
        int row = mf * 16 + lr;
        af[mf] = *(const bf16x8*)&Ab[(row * 8 + ((ks * 4 + lg) ^ (row & 7))) * 8];
      }
      #pragma unroll
      for (int nf = 0; nf < 4; ++nf)
        #pragma unroll
        for (int mf = 0; mf < 4; ++mf)
          acc[nf][mf] = __builtin_amdgcn_mfma_f32_16x16x32_bf16(wf[ks * 4 + nf], af[mf], acc[nf][mf], 0, 0, 0);
    }
    __builtin_amdgcn_s_setprio(0);

    // refill W after last use (register dep orders it); window covers L2 latency
    if (kb < 5) loadW1(kb + 1, wf);
  }
  __syncthreads();  // last As reads done before Hs overlay (nothing useful in flight)

  // ---- h^T -> Hs[64][256] bf16; 8B-unit swizzle up = uu ^ ((lr&3)<<2) ----
  #pragma unroll
  for (int nf = 0; nf < 4; ++nf) {
    f32x4 b1v = *(const f32x4*)(b1 + wid * 64 + nf * 16 + lg * 4);
    #pragma unroll
    for (int mf = 0; mf < 4; ++mf) {
      int row = mf * 16 + lr;
      bf16x4 hb;
      #pragma unroll
      for (int rr = 0; rr < 4; ++rr)
        hb[rr] = (bf16_t)fmaxf(acc[nf][mf][rr] + b1v[rr], 0.f);
      int uu = (wid * 4 + nf) * 4 + lg;
      int up = uu ^ ((lr & 3) << 2);
      *(bf16x4*)&Hs[row * 256 + up * 4] = hb;
    }
  }
  __syncthreads();

  // ---- layer 2: out^T frags = mfma(W2_frag, h_frag); W2 from L1/L2 ----
  const int row2 = wid * 16 + lr;
  f32x4 d2[4];
  #pragma unroll
  for (int i = 0; i < 4; ++i) d2[i] = (f32x4){0.f, 0.f, 0.f, 0.f};
  #pragma unroll
  for (int ks = 0; ks < 8; ++ks) {
    int uu = ks * 8 + lg * 2;
    int up = uu ^ ((lr & 3) << 2);       // bit0 untouched -> 16B stays contiguous
    bf16x8 a2 = *(const bf16x8*)&Hs[row2 * 256 + up * 4];
    const u16* q = W2F + (size_t)ks * 2048 + lane * 8;
    #pragma unroll
    for (int n2f = 0; n2f < 4; ++n2f)
      d2[n2f] = __builtin_amdgcn_mfma_f32_16x16x32_bf16(
          *(const bf16x8*)(q + n2f * 512), a2, d2[n2f], 0, 0, 0);
  }

  // ---- epilogue store ----
  #pragma unroll
  for (int n2f = 0; n2f < 4; ++n2f) {
    f32x4 b2v = *(const f32x4*)(b2 + n2f * 16 + lg * 4);
    f32x4 ov = d2[n2f] + b2v;
    *(f32x4*)&out[(size_t)(e0 + row2) * 64 + n2f * 16 + lg * 4] = ov;
  }
}

extern "C" void kernel_launch(void* const* d_in, const int* in_sizes, int n_in,
                              void* d_out, int out_size, void* d_ws, size_t ws_size,
                              hipStream_t stream) {
  const float* src  = (const float*)d_in[0];
  const float* dst  = (const float*)d_in[1];
  const float* ea   = (const float*)d_in[2];
  const float* u    = (const float*)d_in[3];
  const int* batch  = (const int*)d_in[4];
  const float* W1   = (const float*)d_in[5];
  const float* b1   = (const float*)d_in[6];
  const float* W2   = (const float*)d_in[7];
  const float* b2   = (const float*)d_in[8];
  float* out = (float*)d_out;

  u16* W1F = (u16*)d_ws;          // 98304 u16 frag-ordered W1^T
  u16* W2F = W1F + 98304;         // 16384 u16 frag-ordered W2^T

  prep_w1f<<<384, 256, 0, stream>>>(W1, W1F);
  prep_w2f<<<64, 256, 0, stream>>>(W2, W2F);
  edge_fused<<<NBLK, 256, 0, stream>>>(src, dst, ea, u, batch, W1F, b1, W2F, b2, out);
}